// Round 7
// baseline (81.957 us; speedup 1.0000x reference)
//
#include <hip/hip_runtime.h>
#include <hip/hip_bf16.h>

typedef unsigned short ushort_t;
typedef __attribute__((ext_vector_type(8))) unsigned short u16x8;
typedef __attribute__((ext_vector_type(8))) short bf16x8;
typedef __attribute__((ext_vector_type(4))) float f32x4;
typedef __attribute__((ext_vector_type(2))) float f32x2;

// ---- problem constants ----
constexpr int BB = 8, LL = 100, TT = 129, DD = 512, CH = 512, VV = 1000;
constexpr int M_TXT = BB * LL;          // 800
constexpr int M_OBJ = BB * TT;          // 1032
constexpr int P_SLAB = M_OBJ * DD;      // 528384
constexpr int N_IOU = BB * 3 * TT * TT; // 399384
constexpr int N_VIS = 3 * M_OBJ;        // 3096
constexpr int N_MASK = TT * TT;         // 16641

// output layout (floats)
constexpr int OUT_TEXT = 0;
constexpr int OUT_VIS  = M_TXT * VV;              // 800000
constexpr int OUT_IOU  = OUT_VIS + N_VIS;         // 803096
constexpr int OUT_MASK = OUT_IOU + N_IOU;         // 1202480

// workspace layout (bytes)
constexpr size_t WB_TEXT = 0;                       // 800*512*2
constexpr size_t WB_OBJ  = WB_TEXT + 819200;        // 1032*512*2
constexpr size_t WB_WT1  = WB_OBJ  + 1056768;       // 512*512*2 (transposed)
constexpr size_t WB_WT2  = WB_WT1  + 524288;        // 1000*512*2
constexpr size_t WB_W2T  = WB_WT2  + 1024000;       // 1536*512*2
constexpr size_t WB_W3AT = WB_W2T  + 1572864;       // 512*1536*2
constexpr size_t WB_WS1T = WB_W3AT + 1572864;       // 512*512*2
constexpr size_t WB_WE1T = WB_WS1T + 524288;
constexpr size_t WB_WC1T = WB_WE1T + 524288;
constexpr size_t WB_T1   = WB_WC1T + 524288;        // 800*512*2
constexpr size_t WB_H    = WB_T1   + 819200;        // 1032*1536*2
constexpr size_t WB_P    = WB_H    + 3170304;       // 3*1032*512*4 (fp32)
// total ~16.7 MB

__device__ __forceinline__ ushort_t f2bf(float x) {
    __hip_bfloat16 h = __float2bfloat16(x);
    return *(ushort_t*)&h;
}

// packed 2xf32 VOP3P helpers (gfx90a+: v_pk_add_f32 / v_pk_fma_f32; no pk_max)
__device__ __forceinline__ f32x2 pk_add(f32x2 a, f32x2 b) {
    f32x2 d; asm("v_pk_add_f32 %0, %1, %2" : "=v"(d) : "v"(a), "v"(b)); return d;
}
__device__ __forceinline__ void pk_fma(f32x2& d, f32x2 a, f32x2 b) {
    asm("v_pk_fma_f32 %0, %1, %2, %0" : "+v"(d) : "v"(a), "v"(b));
}
__device__ __forceinline__ f32x2 vlo(f32x4 v) { return __builtin_shufflevector(v, v, 0, 1); }
__device__ __forceinline__ f32x2 vhi(f32x4 v) { return __builtin_shufflevector(v, v, 2, 3); }

// ---------------- prep: act->bf16 + weights->bf16^T (32x64 tiles) ----------------
struct TDesc { const float* src; ushort_t* dst; int R, C, tiles, ctiles; };
struct PrepArgs {
    const float* act_a; ushort_t* act_da; int na4;
    const float* act_b; ushort_t* act_db; int nb4;
    int nact_blocks;
    TDesc t[7];
};

__global__ __launch_bounds__(256)
void prep_kernel(PrepArgs pa)
{
    const int bxg = blockIdx.x;
    if (bxg < pa.nact_blocks) {
        int gid = bxg * 256 + threadIdx.x;
        const float* src; ushort_t* dst;
        if (gid < pa.na4) { src = pa.act_a + gid * 4; dst = pa.act_da + gid * 4; }
        else { gid -= pa.na4; if (gid >= pa.nb4) return; src = pa.act_b + gid * 4; dst = pa.act_db + gid * 4; }
        f32x4 v = *(const f32x4*)src;
        dst[0] = f2bf(v[0]); dst[1] = f2bf(v[1]); dst[2] = f2bf(v[2]); dst[3] = f2bf(v[3]);
        return;
    }
    // 32 (src rows) x 64 (src cols) transpose tile
    __shared__ float tl[32][65];
    int bx = bxg - pa.nact_blocks;
    TDesc e;
    #pragma unroll
    for (int i = 0; i < 7; ++i) {
        e = pa.t[i];
        if (bx < e.tiles) break;
        bx -= e.tiles;
    }
    const int t = threadIdx.x;
    const int rt = bx / e.ctiles, ct = bx - rt * e.ctiles;
    // load: col = ct*64 + (t&63); rows rt*32 + (t>>6) + 4i   (R always multiple of 32)
    {
        const int c = t & 63, ty = t >> 6;
        const int gc = ct * 64 + c;
        const bool cok = gc < e.C;
        const float* sp = e.src + (size_t)(rt * 32) * e.C + gc;
        #pragma unroll
        for (int i = 0; i < 8; ++i) {
            const int rr = ty + i * 4;
            tl[rr][c] = cok ? sp[(size_t)rr * e.C] : 0.0f;
        }
    }
    __syncthreads();
    // store: dst[C][R]; thread: dst row = ct*64 + (t>>2), 8 cols at rt*32 + (t&3)*8
    {
        const int dr = t >> 2, dc0 = (t & 3) << 3;
        const int gdr = ct * 64 + dr;
        if (gdr < e.C) {
            u16x8 v;
            #pragma unroll
            for (int u = 0; u < 8; ++u) v[u] = f2bf(tl[dc0 + u][dr]);
            *(u16x8*)&e.dst[(size_t)gdr * e.R + rt * 32 + dc0] = v;
        }
    }
}

// ---------------- mega: bf16 MFMA GEMM (BK=64) + output-init blocks ----------------
struct GemmDesc {
    const ushort_t* A; int lda;
    const ushort_t* Bt; int ldb;     // B transposed: [N][K]
    const float* bias;
    void* C; int ldc;
    int M, N, K;
    int mode;                        // 0 = f32 out (+bias); 1 = bf16 relu (+bias); 2 = vis atomic
    const float* w2head;             // mode 2
    float* vbase;                    // mode 2: out + OUT_VIS
    int vhead;                       // mode 2: head index
    int ntiles, ntx;
};
struct MegaArgs {
    GemmDesc d[7];
    int gemm_blocks;                 // total gemm tiles (init blocks follow)
    const float *b3b, *bs2, *be2, *bc2;
    float* out;
};

__global__ __launch_bounds__(256)
void mega_kernel(MegaArgs args)
{
    extern __shared__ char smem[];
    if ((int)blockIdx.x >= args.gemm_blocks) {
        // ---- output init path: 4 elems/thread ----
        int g = (blockIdx.x - args.gemm_blocks) * 1024 + threadIdx.x * 4;
        #pragma unroll
        for (int u = 0; u < 4; ++u, ++g) {
            int gg = g;
            if (gg < N_IOU) {
                const int bk = gg / (TT * TT);
                const int k = bk - (bk / 3) * 3;
                args.out[OUT_IOU + gg] = args.b3b[k];
                continue;
            }
            gg -= N_IOU;
            if (gg < N_VIS) {
                const int head = gg - (gg / 3) * 3;
                const float bias = head == 0 ? args.bs2[0] : (head == 1 ? args.be2[0] : args.bc2[0]);
                args.out[OUT_VIS + gg] = bias;
                continue;
            }
            gg -= N_VIS;
            if (gg < N_MASK) {
                const int i = gg / TT, j = gg - i * TT;
                const int d = j - i;
                bool v = false;
                if (i < 128 && d >= 1 && d <= 16) v = true;
                if (!v && (i & 1) == 0 && i <= 110 && d >= 18 && d <= 32 && (d & 1) == 0) v = true;
                if (!v && (i & 3) == 0 && i <= 92  && d >= 36 && d <= 64 && (d & 3) == 0) v = true;
                if (!v && (i & 7) == 0 && i <= 56  && d >= 72 && (d & 7) == 0) v = true;
                args.out[OUT_MASK + gg] = v ? 1.0f : 0.0f;
            }
        }
        return;
    }

    // ---- gemm path ----
    int bx = blockIdx.x, zi = 0;
    while (bx >= args.d[zi].ntiles) { bx -= args.d[zi].ntiles; ++zi; }
    const GemmDesc g = args.d[zi];
    const int tyT = bx / g.ntx, txT = bx - tyT * g.ntx;
    const int m0 = tyT * 128, n0 = txT * 128;

    // layout: ldsA [buf][ks][128*32] then ldsB; 64 KB total
    ushort_t* ldsA = (ushort_t*)smem;
    ushort_t* ldsB = (ushort_t*)smem + 16384;

    const int tid = threadIdx.x;
    const int w = tid >> 6, l = tid & 63;
    const int wr = w >> 1, wc = w & 1;

    const int srow = l >> 2;             // 0..15 within wave chunk
    const int scol = (l & 3) << 3;       // 0/8/16/24
    const int wbase = w << 4;            // wave chunk base row

    f32x4 acc[4][4];
    #pragma unroll
    for (int mi = 0; mi < 4; ++mi)
        #pragma unroll
        for (int ni = 0; ni < 4; ++ni)
            acc[mi][ni] = f32x4{0.f, 0.f, 0.f, 0.f};

    const int nk = g.K >> 6;             // BK=64 steps

    auto stage = [&](int buf, int k0) {
        #pragma unroll
        for (int ks = 0; ks < 2; ++ks) {
            const int sb = ((buf * 2 + ks) << 12);
            #pragma unroll
            for (int q = 0; q < 2; ++q) {
                int gm = m0 + (q << 6) + wbase + srow; if (gm >= g.M) gm = g.M - 1;
                __builtin_amdgcn_global_load_lds(
                    (const __attribute__((address_space(1))) unsigned int*)(g.A + (size_t)gm * g.lda + k0 + (ks << 5) + scol),
                    (__attribute__((address_space(3))) unsigned int*)(ldsA + sb + (((q << 6) + wbase) << 5)),
                    16, 0, 0);
                int gn = n0 + (q << 6) + wbase + srow; if (gn >= g.N) gn = g.N - 1;
                __builtin_amdgcn_global_load_lds(
                    (const __attribute__((address_space(1))) unsigned int*)(g.Bt + (size_t)gn * g.ldb + k0 + (ks << 5) + scol),
                    (__attribute__((address_space(3))) unsigned int*)(ldsB + sb + (((q << 6) + wbase) << 5)),
                    16, 0, 0);
            }
        }
    };

    stage(0, 0);
    int cur = 0;
    const int fr = l & 15, kq = (l >> 4) << 3;

    for (int kt = 0; kt < nk; ++kt) {
        __syncthreads();
        if (kt + 1 < nk) stage(cur ^ 1, (kt + 1) << 6);
        #pragma unroll
        for (int ks = 0; ks < 2; ++ks) {
            const int sb = ((cur * 2 + ks) << 12);
            bf16x8 av[4], bv[4];
            #pragma unroll
            for (int mi = 0; mi < 4; ++mi)
                av[mi] = *(const bf16x8*)(ldsA + sb + ((((wr << 6) + (mi << 4) + fr) << 5) + kq));
            #pragma unroll
            for (int ni = 0; ni < 4; ++ni)
                bv[ni] = *(const bf16x8*)(ldsB + sb + ((((wc << 6) + (ni << 4) + fr) << 5) + kq));
            #pragma unroll
            for (int mi = 0; mi < 4; ++mi)
                #pragma unroll
                for (int ni = 0; ni < 4; ++ni)
                    acc[mi][ni] = __builtin_amdgcn_mfma_f32_16x16x32_bf16(av[mi], bv[ni], acc[mi][ni], 0, 0, 0);
        }
        cur ^= 1;
    }

    // epilogue: C layout col = lane&15, row = (lane>>4)*4 + r
    const int rq = (l >> 4) << 2;
    if (g.mode == 2) {
        float s[4][4];
        #pragma unroll
        for (int mi = 0; mi < 4; ++mi)
            #pragma unroll
            for (int r = 0; r < 4; ++r) s[mi][r] = 0.f;
        #pragma unroll
        for (int ni = 0; ni < 4; ++ni) {
            const int col = n0 + (wc << 6) + (ni << 4) + fr;   // N=512 always in range
            const float bb = g.bias[col];
            const float wv = g.w2head[col];
            #pragma unroll
            for (int mi = 0; mi < 4; ++mi)
                #pragma unroll
                for (int r = 0; r < 4; ++r) {
                    float v = fmaxf(acc[mi][ni][r] + bb, 0.f);
                    s[mi][r] = fmaf(v, wv, s[mi][r]);
                }
        }
        #pragma unroll
        for (int off = 1; off < 16; off <<= 1)
            #pragma unroll
            for (int mi = 0; mi < 4; ++mi)
                #pragma unroll
                for (int r = 0; r < 4; ++r)
                    s[mi][r] += __shfl_xor(s[mi][r], off);
        if (fr == 0) {
            #pragma unroll
            for (int mi = 0; mi < 4; ++mi)
                #pragma unroll
                for (int r = 0; r < 4; ++r) {
                    const int row = m0 + (wr << 6) + (mi << 4) + rq + r;
                    if (row < g.M) atomicAdd(&g.vbase[row * 3 + g.vhead], s[mi][r]);
                }
        }
    } else {
        #pragma unroll
        for (int ni = 0; ni < 4; ++ni) {
            const int col = n0 + (wc << 6) + (ni << 4) + fr;
            const float bb = (g.bias && col < g.N) ? g.bias[col] : 0.f;
            #pragma unroll
            for (int mi = 0; mi < 4; ++mi)
                #pragma unroll
                for (int r = 0; r < 4; ++r) {
                    const int row = m0 + (wr << 6) + (mi << 4) + rq + r;
                    if (row < g.M && col < g.N) {
                        float v = acc[mi][ni][r] + bb;
                        if (g.mode == 1) {
                            v = fmaxf(v, 0.f);
                            ((ushort_t*)g.C)[(size_t)row * g.ldc + col] = f2bf(v);
                        } else {
                            ((float*)g.C)[(size_t)row * g.ldc + col] = v;
                        }
                    }
                }
        }
    }
}

// ---------------- iou (32x32 tile, 2x2 pts/thread, 2x128-c chunks/block, atomic) ----------------
// inner loop packed via v_pk_add_f32 / v_pk_fma_f32 (ReLU stays scalar v_max)
__global__ __launch_bounds__(256)
void iou_kernel(const float* __restrict__ P, const float* __restrict__ w3b,
                float* __restrict__ out)
{
    __shared__ __align__(16) float sP[96 * 132];   // 3 arrays x 32 rows x 132 (pad)
    __shared__ __align__(16) float sW[384];        // w3b chunk transposed [k][c]

    const int tid = threadIdx.x;
    const int b = blockIdx.z >> 1;
    const int half = blockIdx.z & 1;
    const int i0 = blockIdx.y * 32, j0 = blockIdx.x * 32;
    const int idx0 = (i0 + j0) >> 1;
    const int par = (i0 + j0) & 1;

    const int ii = tid >> 4, jj = tid & 15;
    const int o = ((ii + jj + par) >> 1) + 32;

    const f32x2 z2 = {0.f, 0.f};
    // acc[point][k][half]: 24 x f32x2
    f32x2 a00[3][2], a01[3][2], a10[3][2], a11[3][2];
    #pragma unroll
    for (int k = 0; k < 3; ++k)
        #pragma unroll
        for (int h = 0; h < 2; ++h) { a00[k][h] = z2; a01[k][h] = z2; a10[k][h] = z2; a11[k][h] = z2; }

    for (int ph = 0; ph < 2; ++ph) {
        const int c0 = (half << 8) + (ph << 7);    // half*256 + ph*128
        if (ph) __syncthreads();                   // compute of prev phase done
        for (int f = tid; f < 384; f += 256) {
            const int k = f >> 7, c = f & 127;
            sW[f] = w3b[(c0 + c) * 3 + k];
        }
        for (int f = tid; f < 3072; f += 256) {
            const int row = f >> 5;
            const int pos = (f & 31) << 2;
            const int a = row >> 5;
            const int r = row & 31;
            int rg = (a == 0) ? (i0 + r) : (a == 1) ? (idx0 + r) : (j0 + r);
            if (rg > 128) rg = 128;
            f32x4 v = *(const f32x4*)&P[(size_t)a * P_SLAB + ((size_t)(b * TT) + rg) * DD + c0 + pos];
            *(f32x4*)&sP[row * 132 + pos] = v;
        }
        __syncthreads();

        const float* rs0 = &sP[ii * 132];
        const float* rs1 = &sP[(ii + 16) * 132];
        const float* rp0 = &sP[o * 132];
        const float* rp1 = &sP[(o + 8) * 132];
        const float* rp2 = &sP[(o + 16) * 132];
        const float* re0 = &sP[(64 + jj) * 132];
        const float* re1 = &sP[(64 + jj + 16) * 132];

        #pragma unroll 2
        for (int c = 0; c < 128; c += 4) {
            const f32x4 s0 = *(const f32x4*)&rs0[c];
            const f32x4 s1 = *(const f32x4*)&rs1[c];
            const f32x4 p0 = *(const f32x4*)&rp0[c];
            const f32x4 p1 = *(const f32x4*)&rp1[c];
            const f32x4 p2 = *(const f32x4*)&rp2[c];
            const f32x4 e0 = *(const f32x4*)&re0[c];
            const f32x4 e1 = *(const f32x4*)&re1[c];
            const f32x4 w0 = *(const f32x4*)&sW[c];
            const f32x4 w1 = *(const f32x4*)&sW[128 + c];
            const f32x4 w2 = *(const f32x4*)&sW[256 + c];

            #pragma unroll
            for (int h = 0; h < 2; ++h) {
                const f32x2 s0h = h ? vhi(s0) : vlo(s0);
                const f32x2 s1h = h ? vhi(s1) : vlo(s1);
                const f32x2 p0h = h ? vhi(p0) : vlo(p0);
                const f32x2 p1h = h ? vhi(p1) : vlo(p1);
                const f32x2 p2h = h ? vhi(p2) : vlo(p2);
                const f32x2 e0h = h ? vhi(e0) : vlo(e0);
                const f32x2 e1h = h ? vhi(e1) : vlo(e1);
                const f32x2 w0h = h ? vhi(w0) : vlo(w0);
                const f32x2 w1h = h ? vhi(w1) : vlo(w1);
                const f32x2 w2h = h ? vhi(w2) : vlo(w2);

                const f32x2 t00 = pk_add(s0h, e0h);
                const f32x2 t01 = pk_add(s0h, e1h);
                const f32x2 t10 = pk_add(s1h, e0h);
                const f32x2 t11 = pk_add(s1h, e1h);
                const f32x2 v00 = __builtin_elementwise_max(pk_add(t00, p0h), z2);
                const f32x2 v01 = __builtin_elementwise_max(pk_add(t01, p1h), z2);
                const f32x2 v10 = __builtin_elementwise_max(pk_add(t10, p1h), z2);
                const f32x2 v11 = __builtin_elementwise_max(pk_add(t11, p2h), z2);

                pk_fma(a00[0][h], v00, w0h); pk_fma(a00[1][h], v00, w1h); pk_fma(a00[2][h], v00, w2h);
                pk_fma(a01[0][h], v01, w0h); pk_fma(a01[1][h], v01, w1h); pk_fma(a01[2][h], v01, w2h);
                pk_fma(a10[0][h], v10, w0h); pk_fma(a10[1][h], v10, w1h); pk_fma(a10[2][h], v10, w2h);
                pk_fma(a11[0][h], v11, w0h); pk_fma(a11[1][h], v11, w1h); pk_fma(a11[2][h], v11, w2h);
            }
        }
    }

    auto emit = [&](const f32x2 (*acc)[2], int i, int j) {
        if (i <= 128 && j <= 128) {
            #pragma unroll
            for (int k = 0; k < 3; ++k) {
                const float s = acc[k][0][0] + acc[k][0][1] + acc[k][1][0] + acc[k][1][1];
                atomicAdd(&out[OUT_IOU + ((size_t)(b * 3 + k) * TT + i) * TT + j], s);
            }
        }
    };
    emit(a00, i0 + ii, j0 + jj);
    emit(a01, i0 + ii, j0 + jj + 16);
    emit(a10, i0 + ii + 16, j0 + jj);
    emit(a11, i0 + ii + 16, j0 + jj + 16);
}

extern "C" void kernel_launch(void* const* d_in, const int* in_sizes, int n_in,
                              void* d_out, int out_size, void* d_ws, size_t ws_size,
                              hipStream_t stream)
{
    const float* text = (const float*)d_in[0];
    const float* obj  = (const float*)d_in[1];
    const float* w_t1 = (const float*)d_in[2];
    const float* b_t1 = (const float*)d_in[3];
    const float* w_t2 = (const float*)d_in[4];
    const float* b_t2 = (const float*)d_in[5];
    const float* w2   = (const float*)d_in[6];
    const float* b2   = (const float*)d_in[7];
    const float* w3a  = (const float*)d_in[8];
    const float* b3a  = (const float*)d_in[9];
    const float* w3b  = (const float*)d_in[10];
    const float* b3b  = (const float*)d_in[11];
    const float* w_s1 = (const float*)d_in[12];
    const float* b_s1 = (const float*)d_in[13];
    const float* w_s2 = (const float*)d_in[14];
    const float* b_s2 = (const float*)d_in[15];
    const float* w_e1 = (const float*)d_in[16];
    const float* b_e1 = (const float*)d_in[17];
    const float* w_e2 = (const float*)d_in[18];
    const float* b_e2 = (const float*)d_in[19];
    const float* w_c1 = (const float*)d_in[20];
    const float* b_c1 = (const float*)d_in[21];
    const float* w_c2 = (const float*)d_in[22];
    const float* b_c2 = (const float*)d_in[23];

    float* out = (float*)d_out;
    char* ws = (char*)d_ws;
    ushort_t* text_bf = (ushort_t*)(ws + WB_TEXT);
    ushort_t* obj_bf  = (ushort_t*)(ws + WB_OBJ);
    ushort_t* wt1     = (ushort_t*)(ws + WB_WT1);
    ushort_t* wt2     = (ushort_t*)(ws + WB_WT2);
    ushort_t* w2t     = (ushort_t*)(ws + WB_W2T);
    ushort_t* w3at    = (ushort_t*)(ws + WB_W3AT);
    ushort_t* ws1t    = (ushort_t*)(ws + WB_WS1T);
    ushort_t* we1t    = (ushort_t*)(ws + WB_WE1T);
    ushort_t* wc1t    = (ushort_t*)(ws + WB_WC1T);
    ushort_t* T1      = (ushort_t*)(ws + WB_T1);
    ushort_t* H       = (ushort_t*)(ws + WB_H);
    float*    P       = (float*)(ws + WB_P);

    // 1) prep: act conv (916 blocks) + 32x64 weight transposes (1536 tiles)
    {
        PrepArgs pa;
        pa.act_a = text; pa.act_da = text_bf; pa.na4 = (M_TXT * DD) / 4;
        pa.act_b = obj;  pa.act_db = obj_bf;  pa.nb4 = (M_OBJ * DD) / 4;
        pa.nact_blocks = (pa.na4 + pa.nb4 + 255) / 256;
        pa.t[0] = {w_t1, wt1, 512, 512, 128, 8};
        pa.t[1] = {w_t2, wt2, 512, 1000, 256, 16};
        pa.t[2] = {w2, w2t, 512, 1536, 384, 24};
        pa.t[3] = {w3a, w3at, 1536, 512, 384, 8};
        pa.t[4] = {w_s1, ws1t, 512, 512, 128, 8};
        pa.t[5] = {w_e1, we1t, 512, 512, 128, 8};
        pa.t[6] = {w_c1, wc1t, 512, 512, 128, 8};
        prep_kernel<<<dim3(pa.nact_blocks + 1536), dim3(256), 0, stream>>>(pa);
    }
    // 2) mega launch A: gemm {T1 28, H 108} + output-init (410 blocks)
    {
        MegaArgs a{};
        a.d[0] = {text_bf, DD, wt1, DD, b_t1, T1, CH, M_TXT, CH, DD, 1, nullptr, nullptr, 0, 28, 4};
        a.d[1] = {obj_bf, DD, w2t, DD, b2, H, 3 * DD, M_OBJ, 3 * DD, DD, 1, nullptr, nullptr, 0, 108, 12};
        a.gemm_blocks = 136;
        a.b3b = b3b; a.bs2 = b_s2; a.be2 = b_e2; a.bc2 = b_c2; a.out = out;
        const int ninit = (N_IOU + N_VIS + N_MASK + 1023) / 1024;   // 410
        mega_kernel<<<dim3(136 + ninit), dim3(256), 65536, stream>>>(a);
    }
    // 3) mega launch B: text2 (56) + 3x P (f32) + 3x vis (atomic into out_vis)
    {
        MegaArgs a{};
        a.d[0] = {T1, CH, wt2, CH, b_t2, out + OUT_TEXT, VV, M_TXT, VV, CH, 0, nullptr, nullptr, 0, 56, 8};
        a.d[1] = {H + 0 * DD, 3 * DD, w3at + 0 * DD, 3 * DD, b3a, P + 0 * P_SLAB, DD, M_OBJ, DD, DD, 0, nullptr, nullptr, 0, 36, 4};
        a.d[2] = {H + 1 * DD, 3 * DD, w3at + 1 * DD, 3 * DD, nullptr, P + 1 * P_SLAB, DD, M_OBJ, DD, DD, 0, nullptr, nullptr, 0, 36, 4};
        a.d[3] = {H + 2 * DD, 3 * DD, w3at + 2 * DD, 3 * DD, nullptr, P + 2 * P_SLAB, DD, M_OBJ, DD, DD, 0, nullptr, nullptr, 0, 36, 4};
        a.d[4] = {H + 0 * DD, 3 * DD, ws1t, DD, b_s1, nullptr, 0, M_OBJ, CH, DD, 2, w_s2, out + OUT_VIS, 0, 36, 4};
        a.d[5] = {H + 2 * DD, 3 * DD, we1t, DD, b_e1, nullptr, 0, M_OBJ, CH, DD, 2, w_e2, out + OUT_VIS, 1, 36, 4};
        a.d[6] = {H + 1 * DD, 3 * DD, wc1t, DD, b_c1, nullptr, 0, M_OBJ, CH, DD, 2, w_c2, out + OUT_VIS, 2, 36, 4};
        a.gemm_blocks = 272;
        a.b3b = b3b; a.bs2 = b_s2; a.be2 = b_e2; a.bc2 = b_c2; a.out = out;
        mega_kernel<<<dim3(272), dim3(256), 65536, stream>>>(a);
    }
    // 4) iou: 5x5 tiles x (8 b x 2 c-halves) = 400 blocks, atomic accumulate
    iou_kernel<<<dim3(5, 5, 16), dim3(256), 0, stream>>>(P, w3b, out);
}

// Round 8
// 76.963 us; speedup vs baseline: 1.0649x; 1.0649x over previous
//
#include <hip/hip_runtime.h>
#include <hip/hip_bf16.h>

typedef unsigned short ushort_t;
typedef __attribute__((ext_vector_type(8))) unsigned short u16x8;
typedef __attribute__((ext_vector_type(8))) short bf16x8;
typedef __attribute__((ext_vector_type(4))) float f32x4;

// ---- problem constants ----
constexpr int BB = 8, LL = 100, TT = 129, DD = 512, CH = 512, VV = 1000;
constexpr int M_TXT = BB * LL;          // 800
constexpr int M_OBJ = BB * TT;          // 1032
constexpr int P_SLAB = M_OBJ * DD;      // 528384
constexpr int N_IOU = BB * 3 * TT * TT; // 399384
constexpr int N_VIS = 3 * M_OBJ;        // 3096
constexpr int N_MASK = TT * TT;         // 16641

// output layout (floats)
constexpr int OUT_TEXT = 0;
constexpr int OUT_VIS  = M_TXT * VV;              // 800000
constexpr int OUT_IOU  = OUT_VIS + N_VIS;         // 803096
constexpr int OUT_MASK = OUT_IOU + N_IOU;         // 1202480

// workspace layout (bytes)
constexpr size_t WB_TEXT = 0;                       // 800*512*2
constexpr size_t WB_OBJ  = WB_TEXT + 819200;        // 1032*512*2
constexpr size_t WB_WT1  = WB_OBJ  + 1056768;       // 512*512*2 (transposed)
constexpr size_t WB_WT2  = WB_WT1  + 524288;        // 1000*512*2
constexpr size_t WB_W2T  = WB_WT2  + 1024000;       // 1536*512*2
constexpr size_t WB_W3AT = WB_W2T  + 1572864;       // 512*1536*2
constexpr size_t WB_WS1T = WB_W3AT + 1572864;       // 512*512*2
constexpr size_t WB_WE1T = WB_WS1T + 524288;
constexpr size_t WB_WC1T = WB_WE1T + 524288;
constexpr size_t WB_T1   = WB_WC1T + 524288;        // 800*512*2
constexpr size_t WB_H    = WB_T1   + 819200;        // 1032*1536*2
constexpr size_t WB_P    = WB_H    + 3170304;       // 3*1032*512*4 (fp32)
// total ~16.7 MB

__device__ __forceinline__ ushort_t f2bf(float x) {
    __hip_bfloat16 h = __float2bfloat16(x);
    return *(ushort_t*)&h;
}

// ---------------- prep: act->bf16 + weights->bf16^T (32x64 tiles) ----------------
struct TDesc { const float* src; ushort_t* dst; int R, C, tiles, ctiles; };
struct PrepArgs {
    const float* act_a; ushort_t* act_da; int na4;
    const float* act_b; ushort_t* act_db; int nb4;
    int nact_blocks;
    TDesc t[7];
};

__global__ __launch_bounds__(256)
void prep_kernel(PrepArgs pa)
{
    const int bxg = blockIdx.x;
    if (bxg < pa.nact_blocks) {
        int gid = bxg * 256 + threadIdx.x;
        const float* src; ushort_t* dst;
        if (gid < pa.na4) { src = pa.act_a + gid * 4; dst = pa.act_da + gid * 4; }
        else { gid -= pa.na4; if (gid >= pa.nb4) return; src = pa.act_b + gid * 4; dst = pa.act_db + gid * 4; }
        f32x4 v = *(const f32x4*)src;
        dst[0] = f2bf(v[0]); dst[1] = f2bf(v[1]); dst[2] = f2bf(v[2]); dst[3] = f2bf(v[3]);
        return;
    }
    // 32 (src rows) x 64 (src cols) transpose tile
    __shared__ float tl[32][65];
    int bx = bxg - pa.nact_blocks;
    TDesc e;
    #pragma unroll
    for (int i = 0; i < 7; ++i) {
        e = pa.t[i];
        if (bx < e.tiles) break;
        bx -= e.tiles;
    }
    const int t = threadIdx.x;
    const int rt = bx / e.ctiles, ct = bx - rt * e.ctiles;
    // load: col = ct*64 + (t&63); rows rt*32 + (t>>6) + 4i   (R always multiple of 32)
    {
        const int c = t & 63, ty = t >> 6;
        const int gc = ct * 64 + c;
        const bool cok = gc < e.C;
        const float* sp = e.src + (size_t)(rt * 32) * e.C + gc;
        #pragma unroll
        for (int i = 0; i < 8; ++i) {
            const int rr = ty + i * 4;
            tl[rr][c] = cok ? sp[(size_t)rr * e.C] : 0.0f;
        }
    }
    __syncthreads();
    // store: dst[C][R]; thread: dst row = ct*64 + (t>>2), 8 cols at rt*32 + (t&3)*8
    {
        const int dr = t >> 2, dc0 = (t & 3) << 3;
        const int gdr = ct * 64 + dr;
        if (gdr < e.C) {
            u16x8 v;
            #pragma unroll
            for (int u = 0; u < 8; ++u) v[u] = f2bf(tl[dc0 + u][dr]);
            *(u16x8*)&e.dst[(size_t)gdr * e.R + rt * 32 + dc0] = v;
        }
    }
}

// ---------------- mega: bf16 MFMA GEMM (BK=64) + output-init blocks ----------------
struct GemmDesc {
    const ushort_t* A; int lda;
    const ushort_t* Bt; int ldb;     // B transposed: [N][K]
    const float* bias;
    void* C; int ldc;
    int M, N, K;
    int mode;                        // 0 = f32 out (+bias); 1 = bf16 relu (+bias); 2 = vis atomic
    const float* w2head;             // mode 2
    float* vbase;                    // mode 2: out + OUT_VIS
    int vhead;                       // mode 2: head index
    int ntiles, ntx;
};
struct MegaArgs {
    GemmDesc d[7];
    int gemm_blocks;                 // total gemm tiles (init blocks follow)
    const float *b3b, *bs2, *be2, *bc2;
    float* out;
};

__global__ __launch_bounds__(256)
void mega_kernel(MegaArgs args)
{
    extern __shared__ char smem[];
    if ((int)blockIdx.x >= args.gemm_blocks) {
        // ---- output init path: 4 elems/thread ----
        int g = (blockIdx.x - args.gemm_blocks) * 1024 + threadIdx.x * 4;
        #pragma unroll
        for (int u = 0; u < 4; ++u, ++g) {
            int gg = g;
            if (gg < N_IOU) {
                const int bk = gg / (TT * TT);
                const int k = bk - (bk / 3) * 3;
                args.out[OUT_IOU + gg] = args.b3b[k];
                continue;
            }
            gg -= N_IOU;
            if (gg < N_VIS) {
                const int head = gg - (gg / 3) * 3;
                const float bias = head == 0 ? args.bs2[0] : (head == 1 ? args.be2[0] : args.bc2[0]);
                args.out[OUT_VIS + gg] = bias;
                continue;
            }
            gg -= N_VIS;
            if (gg < N_MASK) {
                const int i = gg / TT, j = gg - i * TT;
                const int d = j - i;
                bool v = false;
                if (i < 128 && d >= 1 && d <= 16) v = true;
                if (!v && (i & 1) == 0 && i <= 110 && d >= 18 && d <= 32 && (d & 1) == 0) v = true;
                if (!v && (i & 3) == 0 && i <= 92  && d >= 36 && d <= 64 && (d & 3) == 0) v = true;
                if (!v && (i & 7) == 0 && i <= 56  && d >= 72 && (d & 7) == 0) v = true;
                args.out[OUT_MASK + gg] = v ? 1.0f : 0.0f;
            }
        }
        return;
    }

    // ---- gemm path ----
    int bx = blockIdx.x, zi = 0;
    while (bx >= args.d[zi].ntiles) { bx -= args.d[zi].ntiles; ++zi; }
    const GemmDesc g = args.d[zi];
    const int tyT = bx / g.ntx, txT = bx - tyT * g.ntx;
    const int m0 = tyT * 128, n0 = txT * 128;

    // layout: ldsA [buf][ks][128*32] then ldsB; 64 KB total
    ushort_t* ldsA = (ushort_t*)smem;
    ushort_t* ldsB = (ushort_t*)smem + 16384;

    const int tid = threadIdx.x;
    const int w = tid >> 6, l = tid & 63;
    const int wr = w >> 1, wc = w & 1;

    const int srow = l >> 2;             // 0..15 within wave chunk
    const int scol = (l & 3) << 3;       // 0/8/16/24
    const int wbase = w << 4;            // wave chunk base row

    f32x4 acc[4][4];
    #pragma unroll
    for (int mi = 0; mi < 4; ++mi)
        #pragma unroll
        for (int ni = 0; ni < 4; ++ni)
            acc[mi][ni] = f32x4{0.f, 0.f, 0.f, 0.f};

    const int nk = g.K >> 6;             // BK=64 steps

    auto stage = [&](int buf, int k0) {
        #pragma unroll
        for (int ks = 0; ks < 2; ++ks) {
            const int sb = ((buf * 2 + ks) << 12);
            #pragma unroll
            for (int q = 0; q < 2; ++q) {
                int gm = m0 + (q << 6) + wbase + srow; if (gm >= g.M) gm = g.M - 1;
                __builtin_amdgcn_global_load_lds(
                    (const __attribute__((address_space(1))) unsigned int*)(g.A + (size_t)gm * g.lda + k0 + (ks << 5) + scol),
                    (__attribute__((address_space(3))) unsigned int*)(ldsA + sb + (((q << 6) + wbase) << 5)),
                    16, 0, 0);
                int gn = n0 + (q << 6) + wbase + srow; if (gn >= g.N) gn = g.N - 1;
                __builtin_amdgcn_global_load_lds(
                    (const __attribute__((address_space(1))) unsigned int*)(g.Bt + (size_t)gn * g.ldb + k0 + (ks << 5) + scol),
                    (__attribute__((address_space(3))) unsigned int*)(ldsB + sb + (((q << 6) + wbase) << 5)),
                    16, 0, 0);
            }
        }
    };

    stage(0, 0);
    int cur = 0;
    const int fr = l & 15, kq = (l >> 4) << 3;

    for (int kt = 0; kt < nk; ++kt) {
        __syncthreads();
        if (kt + 1 < nk) stage(cur ^ 1, (kt + 1) << 6);
        #pragma unroll
        for (int ks = 0; ks < 2; ++ks) {
            const int sb = ((cur * 2 + ks) << 12);
            bf16x8 av[4], bv[4];
            #pragma unroll
            for (int mi = 0; mi < 4; ++mi)
                av[mi] = *(const bf16x8*)(ldsA + sb + ((((wr << 6) + (mi << 4) + fr) << 5) + kq));
            #pragma unroll
            for (int ni = 0; ni < 4; ++ni)
                bv[ni] = *(const bf16x8*)(ldsB + sb + ((((wc << 6) + (ni << 4) + fr) << 5) + kq));
            #pragma unroll
            for (int mi = 0; mi < 4; ++mi)
                #pragma unroll
                for (int ni = 0; ni < 4; ++ni)
                    acc[mi][ni] = __builtin_amdgcn_mfma_f32_16x16x32_bf16(av[mi], bv[ni], acc[mi][ni], 0, 0, 0);
        }
        cur ^= 1;
    }

    // epilogue: C layout col = lane&15, row = (lane>>4)*4 + r
    const int rq = (l >> 4) << 2;
    if (g.mode == 2) {
        float s[4][4];
        #pragma unroll
        for (int mi = 0; mi < 4; ++mi)
            #pragma unroll
            for (int r = 0; r < 4; ++r) s[mi][r] = 0.f;
        #pragma unroll
        for (int ni = 0; ni < 4; ++ni) {
            const int col = n0 + (wc << 6) + (ni << 4) + fr;   // N=512 always in range
            const float bb = g.bias[col];
            const float wv = g.w2head[col];
            #pragma unroll
            for (int mi = 0; mi < 4; ++mi)
                #pragma unroll
                for (int r = 0; r < 4; ++r) {
                    float v = fmaxf(acc[mi][ni][r] + bb, 0.f);
                    s[mi][r] = fmaf(v, wv, s[mi][r]);
                }
        }
        #pragma unroll
        for (int off = 1; off < 16; off <<= 1)
            #pragma unroll
            for (int mi = 0; mi < 4; ++mi)
                #pragma unroll
                for (int r = 0; r < 4; ++r)
                    s[mi][r] += __shfl_xor(s[mi][r], off);
        if (fr == 0) {
            #pragma unroll
            for (int mi = 0; mi < 4; ++mi)
                #pragma unroll
                for (int r = 0; r < 4; ++r) {
                    const int row = m0 + (wr << 6) + (mi << 4) + rq + r;
                    if (row < g.M) atomicAdd(&g.vbase[row * 3 + g.vhead], s[mi][r]);
                }
        }
    } else {
        #pragma unroll
        for (int ni = 0; ni < 4; ++ni) {
            const int col = n0 + (wc << 6) + (ni << 4) + fr;
            const float bb = (g.bias && col < g.N) ? g.bias[col] : 0.f;
            #pragma unroll
            for (int mi = 0; mi < 4; ++mi)
                #pragma unroll
                for (int r = 0; r < 4; ++r) {
                    const int row = m0 + (wr << 6) + (mi << 4) + rq + r;
                    if (row < g.M && col < g.N) {
                        float v = acc[mi][ni][r] + bb;
                        if (g.mode == 1) {
                            v = fmaxf(v, 0.f);
                            ((ushort_t*)g.C)[(size_t)row * g.ldc + col] = f2bf(v);
                        } else {
                            ((float*)g.C)[(size_t)row * g.ldc + col] = v;
                        }
                    }
                }
        }
    }
}

// ---------------- iou (32x32 tile, 2x2 pts/thread, 2x128-c chunks/block, atomic) ----------------
// r6-proven elementwise f32x4 inner loop; both w3b chunks preloaded once.
__global__ __launch_bounds__(256)
void iou_kernel(const float* __restrict__ P, const float* __restrict__ w3b,
                float* __restrict__ out)
{
    __shared__ __align__(16) float sP[96 * 132];   // 3 arrays x 32 rows x 132 (pad)
    __shared__ __align__(16) float sW[768];        // w3b transposed [ph][k][c]

    const int tid = threadIdx.x;
    const int b = blockIdx.z >> 1;
    const int half = blockIdx.z & 1;
    const int i0 = blockIdx.y * 32, j0 = blockIdx.x * 32;
    const int idx0 = (i0 + j0) >> 1;
    const int par = (i0 + j0) & 1;

    // preload both c-chunks of w3b for this half: sW[ph*384 + k*128 + c]
    for (int f = tid; f < 768; f += 256) {
        const int ph = f / 384;
        const int rem = f - ph * 384;
        const int k = rem >> 7, c = rem & 127;
        sW[f] = w3b[((half << 8) + (ph << 7) + c) * 3 + k];
    }

    const int ii = tid >> 4, jj = tid & 15;
    const int o = ((ii + jj + par) >> 1) + 32;

    const f32x4 z4 = {0.f, 0.f, 0.f, 0.f};
    f32x4 av00[3], av01[3], av10[3], av11[3];
    #pragma unroll
    for (int k = 0; k < 3; ++k) { av00[k] = z4; av01[k] = z4; av10[k] = z4; av11[k] = z4; }

    for (int ph = 0; ph < 2; ++ph) {
        const int c0 = (half << 8) + (ph << 7);    // half*256 + ph*128
        if (ph) __syncthreads();                   // compute of prev phase done
        for (int f = tid; f < 3072; f += 256) {
            const int row = f >> 5;
            const int pos = (f & 31) << 2;
            const int a = row >> 5;
            const int r = row & 31;
            int rg = (a == 0) ? (i0 + r) : (a == 1) ? (idx0 + r) : (j0 + r);
            if (rg > 128) rg = 128;
            f32x4 v = *(const f32x4*)&P[(size_t)a * P_SLAB + ((size_t)(b * TT) + rg) * DD + c0 + pos];
            *(f32x4*)&sP[row * 132 + pos] = v;
        }
        __syncthreads();

        const float* rs0 = &sP[ii * 132];
        const float* rs1 = &sP[(ii + 16) * 132];
        const float* rp0 = &sP[o * 132];
        const float* rp1 = &sP[(o + 8) * 132];
        const float* rp2 = &sP[(o + 16) * 132];
        const float* re0 = &sP[(64 + jj) * 132];
        const float* re1 = &sP[(64 + jj + 16) * 132];
        const float* swp = &sW[ph * 384];

        #pragma unroll 2
        for (int c = 0; c < 128; c += 4) {
            const f32x4 s0 = *(const f32x4*)&rs0[c];
            const f32x4 s1 = *(const f32x4*)&rs1[c];
            const f32x4 p0 = *(const f32x4*)&rp0[c];
            const f32x4 p1 = *(const f32x4*)&rp1[c];
            const f32x4 p2 = *(const f32x4*)&rp2[c];
            const f32x4 e0 = *(const f32x4*)&re0[c];
            const f32x4 e1 = *(const f32x4*)&re1[c];
            const f32x4 w0 = *(const f32x4*)&swp[c];
            const f32x4 w1 = *(const f32x4*)&swp[128 + c];
            const f32x4 w2 = *(const f32x4*)&swp[256 + c];

            const f32x4 t00 = s0 + e0, t01 = s0 + e1, t10 = s1 + e0, t11 = s1 + e1;
            const f32x4 v00 = __builtin_elementwise_max(t00 + p0, z4);
            const f32x4 v01 = __builtin_elementwise_max(t01 + p1, z4);
            const f32x4 v10 = __builtin_elementwise_max(t10 + p1, z4);
            const f32x4 v11 = __builtin_elementwise_max(t11 + p2, z4);

            av00[0] = __builtin_elementwise_fma(v00, w0, av00[0]);
            av00[1] = __builtin_elementwise_fma(v00, w1, av00[1]);
            av00[2] = __builtin_elementwise_fma(v00, w2, av00[2]);
            av01[0] = __builtin_elementwise_fma(v01, w0, av01[0]);
            av01[1] = __builtin_elementwise_fma(v01, w1, av01[1]);
            av01[2] = __builtin_elementwise_fma(v01, w2, av01[2]);
            av10[0] = __builtin_elementwise_fma(v10, w0, av10[0]);
            av10[1] = __builtin_elementwise_fma(v10, w1, av10[1]);
            av10[2] = __builtin_elementwise_fma(v10, w2, av10[2]);
            av11[0] = __builtin_elementwise_fma(v11, w0, av11[0]);
            av11[1] = __builtin_elementwise_fma(v11, w1, av11[1]);
            av11[2] = __builtin_elementwise_fma(v11, w2, av11[2]);
        }
    }

    auto emit = [&](const f32x4* acc, int i, int j) {
        if (i <= 128 && j <= 128) {
            #pragma unroll
            for (int k = 0; k < 3; ++k) {
                const float s = acc[k][0] + acc[k][1] + acc[k][2] + acc[k][3];
                atomicAdd(&out[OUT_IOU + ((size_t)(b * 3 + k) * TT + i) * TT + j], s);
            }
        }
    };
    emit(av00, i0 + ii, j0 + jj);
    emit(av01, i0 + ii, j0 + jj + 16);
    emit(av10, i0 + ii + 16, j0 + jj);
    emit(av11, i0 + ii + 16, j0 + jj + 16);
}

extern "C" void kernel_launch(void* const* d_in, const int* in_sizes, int n_in,
                              void* d_out, int out_size, void* d_ws, size_t ws_size,
                              hipStream_t stream)
{
    const float* text = (const float*)d_in[0];
    const float* obj  = (const float*)d_in[1];
    const float* w_t1 = (const float*)d_in[2];
    const float* b_t1 = (const float*)d_in[3];
    const float* w_t2 = (const float*)d_in[4];
    const float* b_t2 = (const float*)d_in[5];
    const float* w2   = (const float*)d_in[6];
    const float* b2   = (const float*)d_in[7];
    const float* w3a  = (const float*)d_in[8];
    const float* b3a  = (const float*)d_in[9];
    const float* w3b  = (const float*)d_in[10];
    const float* b3b  = (const float*)d_in[11];
    const float* w_s1 = (const float*)d_in[12];
    const float* b_s1 = (const float*)d_in[13];
    const float* w_s2 = (const float*)d_in[14];
    const float* b_s2 = (const float*)d_in[15];
    const float* w_e1 = (const float*)d_in[16];
    const float* b_e1 = (const float*)d_in[17];
    const float* w_e2 = (const float*)d_in[18];
    const float* b_e2 = (const float*)d_in[19];
    const float* w_c1 = (const float*)d_in[20];
    const float* b_c1 = (const float*)d_in[21];
    const float* w_c2 = (const float*)d_in[22];
    const float* b_c2 = (const float*)d_in[23];

    float* out = (float*)d_out;
    char* ws = (char*)d_ws;
    ushort_t* text_bf = (ushort_t*)(ws + WB_TEXT);
    ushort_t* obj_bf  = (ushort_t*)(ws + WB_OBJ);
    ushort_t* wt1     = (ushort_t*)(ws + WB_WT1);
    ushort_t* wt2     = (ushort_t*)(ws + WB_WT2);
    ushort_t* w2t     = (ushort_t*)(ws + WB_W2T);
    ushort_t* w3at    = (ushort_t*)(ws + WB_W3AT);
    ushort_t* ws1t    = (ushort_t*)(ws + WB_WS1T);
    ushort_t* we1t    = (ushort_t*)(ws + WB_WE1T);
    ushort_t* wc1t    = (ushort_t*)(ws + WB_WC1T);
    ushort_t* T1      = (ushort_t*)(ws + WB_T1);
    ushort_t* H       = (ushort_t*)(ws + WB_H);
    float*    P       = (float*)(ws + WB_P);

    // 1) prep: act conv (916 blocks) + 32x64 weight transposes (1536 tiles)
    {
        PrepArgs pa;
        pa.act_a = text; pa.act_da = text_bf; pa.na4 = (M_TXT * DD) / 4;
        pa.act_b = obj;  pa.act_db = obj_bf;  pa.nb4 = (M_OBJ * DD) / 4;
        pa.nact_blocks = (pa.na4 + pa.nb4 + 255) / 256;
        pa.t[0] = {w_t1, wt1, 512, 512, 128, 8};
        pa.t[1] = {w_t2, wt2, 512, 1000, 256, 16};
        pa.t[2] = {w2, w2t, 512, 1536, 384, 24};
        pa.t[3] = {w3a, w3at, 1536, 512, 384, 8};
        pa.t[4] = {w_s1, ws1t, 512, 512, 128, 8};
        pa.t[5] = {w_e1, we1t, 512, 512, 128, 8};
        pa.t[6] = {w_c1, wc1t, 512, 512, 128, 8};
        prep_kernel<<<dim3(pa.nact_blocks + 1536), dim3(256), 0, stream>>>(pa);
    }
    // 2) mega launch A: gemm {T1 28, H 108} + output-init (410 blocks)
    {
        MegaArgs a{};
        a.d[0] = {text_bf, DD, wt1, DD, b_t1, T1, CH, M_TXT, CH, DD, 1, nullptr, nullptr, 0, 28, 4};
        a.d[1] = {obj_bf, DD, w2t, DD, b2, H, 3 * DD, M_OBJ, 3 * DD, DD, 1, nullptr, nullptr, 0, 108, 12};
        a.gemm_blocks = 136;
        a.b3b = b3b; a.bs2 = b_s2; a.be2 = b_e2; a.bc2 = b_c2; a.out = out;
        const int ninit = (N_IOU + N_VIS + N_MASK + 1023) / 1024;   // 410
        mega_kernel<<<dim3(136 + ninit), dim3(256), 65536, stream>>>(a);
    }
    // 3) mega launch B: text2 (56) + 3x P (f32) + 3x vis (atomic into out_vis)
    {
        MegaArgs a{};
        a.d[0] = {T1, CH, wt2, CH, b_t2, out + OUT_TEXT, VV, M_TXT, VV, CH, 0, nullptr, nullptr, 0, 56, 8};
        a.d[1] = {H + 0 * DD, 3 * DD, w3at + 0 * DD, 3 * DD, b3a, P + 0 * P_SLAB, DD, M_OBJ, DD, DD, 0, nullptr, nullptr, 0, 36, 4};
        a.d[2] = {H + 1 * DD, 3 * DD, w3at + 1 * DD, 3 * DD, nullptr, P + 1 * P_SLAB, DD, M_OBJ, DD, DD, 0, nullptr, nullptr, 0, 36, 4};
        a.d[3] = {H + 2 * DD, 3 * DD, w3at + 2 * DD, 3 * DD, nullptr, P + 2 * P_SLAB, DD, M_OBJ, DD, DD, 0, nullptr, nullptr, 0, 36, 4};
        a.d[4] = {H + 0 * DD, 3 * DD, ws1t, DD, b_s1, nullptr, 0, M_OBJ, CH, DD, 2, w_s2, out + OUT_VIS, 0, 36, 4};
        a.d[5] = {H + 2 * DD, 3 * DD, we1t, DD, b_e1, nullptr, 0, M_OBJ, CH, DD, 2, w_e2, out + OUT_VIS, 1, 36, 4};
        a.d[6] = {H + 1 * DD, 3 * DD, wc1t, DD, b_c1, nullptr, 0, M_OBJ, CH, DD, 2, w_c2, out + OUT_VIS, 2, 36, 4};
        a.gemm_blocks = 272;
        a.b3b = b3b; a.bs2 = b_s2; a.be2 = b_e2; a.bc2 = b_c2; a.out = out;
        mega_kernel<<<dim3(272), dim3(256), 65536, stream>>>(a);
    }
    // 4) iou: 5x5 tiles x (8 b x 2 c-halves) = 400 blocks, atomic accumulate
    iou_kernel<<<dim3(5, 5, 16), dim3(256), 0, stream>>>(P, w3b, out);
}